// Round 5
// baseline (156.813 us; speedup 1.0000x reference)
//
#include <hip/hip_runtime.h>
#include <math.h>

#define SCALE_INV 20.0f
#define EXPK 28.853900817779268f   // SCALE_INV * log2(e)
#define LN2F 0.6931471805599453f   // SCALE_INV / EXPK

typedef __bf16 bf16x8 __attribute__((ext_vector_type(8)));
typedef float  f32x4  __attribute__((ext_vector_type(4)));

// ---------------------------------------------------------------------------
// 1. fused head GEMM + bias + l2norm -> nxb, nxe. grid 256 x 256 thr.
//    32 rows/block, K-chunks of 64, fp32 w convert-on-stage (round-2 proven).
//    Also zeroes cspart (32 floats/block) and accs (block 0) for later passes.
// ---------------------------------------------------------------------------
__global__ __launch_bounds__(256) void k_headnorm(const float* __restrict__ e,
                                                  const float* __restrict__ w,
                                                  const float* __restrict__ hb,
                                                  __bf16* __restrict__ nxb,
                                                  __bf16* __restrict__ nxe,
                                                  float* __restrict__ cspart,
                                                  float* __restrict__ accs) {
  __shared__ __bf16 Ab[32 * 72];    // 32 rows x 64 k
  __shared__ __bf16 Bb[128 * 72];   // 128 h  x 64 k
  __shared__ float  xt[32 * 132];   // output tile for norm
  __shared__ float  hbl[128];
  const int t  = threadIdx.x;
  const int rt = blockIdx.x;
  if (t < 128) hbl[t] = hb[t];
  if (t < 32) cspart[rt * 32 + t] = 0.0f;          // zero neg-accumulator
  if (rt == 0 && t >= 128 && t < 132) accs[t - 128] = 0.0f;

  const int arow = t >> 3, akoff = (t & 7) * 8;   // A: 8 floats/thread
  const int brow = t >> 1, bkoff = (t & 1) * 32;  // B: 32 floats/thread
  float4 ar[2], br[8];
  {
    const float* p = &e[(rt * 32 + arow) * 768 + akoff];
    ar[0] = *(const float4*)p; ar[1] = *(const float4*)(p + 4);
    const float* q = &w[brow * 768 + bkoff];
    for (int i = 0; i < 8; i++) br[i] = *(const float4*)(q + 4 * i);
  }

  const int wv = t >> 6, lane = t & 63;
  const int quad = lane >> 4, lrow = lane & 15;
  const int rb = wv & 1, cb = wv >> 1;
  f32x4 acc[4];
  f32x4 zero = {0.f, 0.f, 0.f, 0.f};
  for (int j = 0; j < 4; j++) acc[j] = zero;

  for (int it = 0; it < 12; it++) {
    {
      __bf16 ta[8];
      const float* f = (const float*)ar;
      for (int i = 0; i < 8; i++) ta[i] = (__bf16)f[i];
      *(bf16x8*)&Ab[arow * 72 + akoff] = *(bf16x8*)ta;
      const float* g = (const float*)br;
      for (int seg = 0; seg < 4; seg++) {
        __bf16 tb[8];
        for (int i = 0; i < 8; i++) tb[i] = (__bf16)g[seg * 8 + i];
        *(bf16x8*)&Bb[brow * 72 + bkoff + seg * 8] = *(bf16x8*)tb;
      }
    }
    __syncthreads();
    if (it < 11) {
      int kb = (it + 1) * 64;
      const float* p = &e[(rt * 32 + arow) * 768 + kb + akoff];
      ar[0] = *(const float4*)p; ar[1] = *(const float4*)(p + 4);
      const float* q = &w[brow * 768 + kb + bkoff];
      for (int i = 0; i < 8; i++) br[i] = *(const float4*)(q + 4 * i);
    }
    for (int kc = 0; kc < 2; kc++) {
      bf16x8 a = *(const bf16x8*)&Ab[(rb * 16 + lrow) * 72 + kc * 32 + quad * 8];
      for (int j = 0; j < 4; j++) {
        bf16x8 b = *(const bf16x8*)&Bb[(cb * 64 + j * 16 + lrow) * 72 + kc * 32 + quad * 8];
        acc[j] = __builtin_amdgcn_mfma_f32_16x16x32_bf16(a, b, acc[j], 0, 0, 0);
      }
    }
    __syncthreads();
  }

  for (int j = 0; j < 4; j++)
    for (int r = 0; r < 4; r++) {
      int row = rb * 16 + quad * 4 + r;
      int col = cb * 64 + j * 16 + lrow;
      xt[row * 132 + col] = acc[j][r] + hbl[col];
    }
  __syncthreads();
  {
    int row = t >> 3, c0 = (t & 7) * 16;
    float v[16];
    float s = 0.0f;
    for (int i = 0; i < 4; i++) {
      float4 f = *(const float4*)&xt[row * 132 + c0 + i * 4];
      v[i * 4] = f.x; v[i * 4 + 1] = f.y; v[i * 4 + 2] = f.z; v[i * 4 + 3] = f.w;
    }
    for (int i = 0; i < 16; i++) s += v[i] * v[i];
    s += __shfl_xor(s, 1, 64);
    s += __shfl_xor(s, 2, 64);
    s += __shfl_xor(s, 4, 64);
    float inv = 1.0f / fmaxf(sqrtf(s), 1e-12f);
    __bf16 o[16], oe[16];
    for (int i = 0; i < 16; i++) {
      float nv = v[i] * inv;
      o[i]  = (__bf16)nv;
      oe[i] = (__bf16)(nv * EXPK);
    }
    __bf16* dst = &nxb[(rt * 32 + row) * 128 + c0];
    *(bf16x8*)dst       = *(bf16x8*)o;
    *(bf16x8*)(dst + 8) = *(bf16x8*)(o + 8);
    __bf16* dse = &nxe[(rt * 32 + row) * 128 + c0];
    *(bf16x8*)dse       = *(bf16x8*)oe;
    *(bf16x8*)(dse + 8) = *(bf16x8*)(oe + 8);
  }
}

// ---------------------------------------------------------------------------
// 2. symmetric off-class colsum. grid (64, 8), 256 thr.
//    Each unordered class pair computed ONCE; exp'd tile reduced both ways.
//    B fragments for kc=0,1 hoisted to registers (64 VGPR) after staging:
//    per-tile LDS reads drop 40 -> 24 per wave (kernel was LDS-issue-bound).
// ---------------------------------------------------------------------------
__global__ __launch_bounds__(256) void k_colsum(const __bf16* __restrict__ nxb,
                                                const __bf16* __restrict__ nxe,
                                                float* __restrict__ cspart) {
  __shared__ __bf16 At[128 * 136];
  __shared__ __bf16 Bt[128 * 136];
  __shared__ float  colpart[4 * 128];
  const int t    = threadIdx.x;
  const int cj   = blockIdx.x;
  const int rs   = blockIdx.y;
  const int w    = t >> 6, lane = t & 63;
  const int quad = lane >> 4, lrow = lane & 15;
  const int sr   = t >> 4, sseg = t & 15;

  // stage B = prescaled columns of class cj
  for (int it = 0; it < 8; it++) {
    int r = sr + it * 16;
    *(bf16x8*)&Bt[r * 136 + sseg * 8] =
        *(const bf16x8*)&nxe[(cj * 128 + r) * 128 + sseg * 8];
  }
  // partner-tile list (m=32 wrap pair only counted once, from cj<32)
  int tiles[4], nt = 0;
  for (int mm = 0; mm < 4; mm++) {
    int m = rs * 4 + 1 + mm;
    if (m < 32 || cj < 32) tiles[nt++] = (cj + m) & 63;
  }
  bf16x8 pre[8];
  for (int it = 0; it < 8; it++)
    pre[it] = *(const bf16x8*)&nxb[(tiles[0] * 128 + sr + it * 16) * 128 + sseg * 8];

  float colacc[8];
  for (int j = 0; j < 8; j++) colacc[j] = 0.0f;

  __syncthreads();  // Bt visible -> hoist kc=0,1 B fragments into registers
  bf16x8 bfr[2][8];
  for (int kc = 0; kc < 2; kc++)
    for (int j = 0; j < 8; j++)
      bfr[kc][j] = *(const bf16x8*)&Bt[(j * 16 + lrow) * 136 + kc * 32 + quad * 8];

  for (int ti = 0; ti < nt; ti++) {
    const int ci = tiles[ti];
    for (int it = 0; it < 8; it++)
      *(bf16x8*)&At[(sr + it * 16) * 136 + sseg * 8] = pre[it];
    __syncthreads();
    if (ti + 1 < nt) {
      int cn = tiles[ti + 1];
      for (int it = 0; it < 8; it++)
        pre[it] = *(const bf16x8*)&nxb[(cn * 128 + sr + it * 16) * 128 + sseg * 8];
    }
    f32x4 acc[2][8];
    f32x4 zero = {0.0f, 0.0f, 0.0f, 0.0f};
    for (int i = 0; i < 2; i++)
      for (int j = 0; j < 8; j++) acc[i][j] = zero;
    for (int kc = 0; kc < 2; kc++) {
      bf16x8 a0 = *(const bf16x8*)&At[(w * 32 + lrow) * 136 + kc * 32 + quad * 8];
      bf16x8 a1 = *(const bf16x8*)&At[(w * 32 + 16 + lrow) * 136 + kc * 32 + quad * 8];
      for (int j = 0; j < 8; j++) {
        acc[0][j] = __builtin_amdgcn_mfma_f32_16x16x32_bf16(a0, bfr[kc][j], acc[0][j], 0, 0, 0);
        acc[1][j] = __builtin_amdgcn_mfma_f32_16x16x32_bf16(a1, bfr[kc][j], acc[1][j], 0, 0, 0);
      }
    }
    for (int kc = 2; kc < 4; kc++) {
      bf16x8 a0 = *(const bf16x8*)&At[(w * 32 + lrow) * 136 + kc * 32 + quad * 8];
      bf16x8 a1 = *(const bf16x8*)&At[(w * 32 + 16 + lrow) * 136 + kc * 32 + quad * 8];
      for (int j = 0; j < 8; j++) {
        bf16x8 b = *(const bf16x8*)&Bt[(j * 16 + lrow) * 136 + kc * 32 + quad * 8];
        acc[0][j] = __builtin_amdgcn_mfma_f32_16x16x32_bf16(a0, b, acc[0][j], 0, 0, 0);
        acc[1][j] = __builtin_amdgcn_mfma_f32_16x16x32_bf16(a1, b, acc[1][j], 0, 0, 0);
      }
    }
    // exp once; accumulate col sums (for cj) and row sums (for ci)
    float rsum[2][4];
    for (int i = 0; i < 2; i++)
      for (int r = 0; r < 4; r++) rsum[i][r] = 0.0f;
    for (int i = 0; i < 2; i++)
      for (int j = 0; j < 8; j++)
        for (int r = 0; r < 4; r++) {
          float ev = exp2f(acc[i][j][r]);
          colacc[j]  += ev;
          rsum[i][r] += ev;
        }
    for (int i = 0; i < 2; i++)
      for (int r = 0; r < 4; r++) {
        float v = rsum[i][r];
        v += __shfl_xor(v, 1, 64);
        v += __shfl_xor(v, 2, 64);
        v += __shfl_xor(v, 4, 64);
        v += __shfl_xor(v, 8, 64);
        if (lrow == 0)
          atomicAdd(&cspart[ci * 128 + w * 32 + i * 16 + quad * 4 + r], v);
      }
    __syncthreads();
  }

  // col-sum reduction (over quads, then waves), one atomic per column
  for (int j = 0; j < 8; j++) {
    float v = colacc[j];
    v += __shfl_xor(v, 16, 64);
    v += __shfl_xor(v, 32, 64);
    if (lane < 16) colpart[w * 128 + j * 16 + lane] = v;
  }
  __syncthreads();
  if (t < 128) {
    float s = colpart[t] + colpart[128 + t] + colpart[256 + t] + colpart[384 + t];
    atomicAdd(&cspart[cj * 128 + t], s);
  }
}

// ---------------------------------------------------------------------------
// 3. fused proto + instance loss + finalize. grid (64, 2), 256 thr.
// ---------------------------------------------------------------------------
__global__ __launch_bounds__(256) void k_fused(const __bf16* __restrict__ nxb,
                                               const __bf16* __restrict__ nxe,
                                               const float* __restrict__ proto,
                                               const float* __restrict__ cspart,
                                               float* __restrict__ accs,
                                               float* __restrict__ out) {
  __shared__ __bf16 Xt[64 * 136];
  __shared__ __bf16 XtE[128 * 136];
  __shared__ __bf16 PtE[64 * 136];
  __shared__ float  negl[128];
  const int t = threadIdx.x, cls = blockIdx.x, half = blockIdx.y;
  const int sr = t >> 4, sseg = t & 15;

  // norm protos into PtE: 4 threads per row, 32 elems each
  {
    const int rw = t >> 2, part = t & 3;
    float v[32];
    float s = 0.0f;
    const float* p = &proto[rw * 128 + part * 32];
    for (int i = 0; i < 8; i++) {
      float4 f = *(const float4*)(p + 4 * i);
      v[i * 4] = f.x; v[i * 4 + 1] = f.y; v[i * 4 + 2] = f.z; v[i * 4 + 3] = f.w;
      s += f.x * f.x + f.y * f.y + f.z * f.z + f.w * f.w;
    }
    s += __shfl_xor(s, 1, 64);
    s += __shfl_xor(s, 2, 64);
    float inv = EXPK / fmaxf(sqrtf(s), 1e-12f);
    __bf16 o[32];
    for (int i = 0; i < 32; i++) o[i] = (__bf16)(v[i] * inv);
    __bf16* dst = &PtE[rw * 136 + part * 32];
    for (int i = 0; i < 4; i++) *(bf16x8*)(dst + i * 8) = *(bf16x8*)(o + i * 8);
  }
  for (int it = 0; it < 4; it++) {
    int r = sr + it * 16;
    *(bf16x8*)&Xt[r * 136 + sseg * 8] =
        *(const bf16x8*)&nxb[(cls * 128 + half * 64 + r) * 128 + sseg * 8];
  }
  for (int it = 0; it < 8; it++) {
    int r = sr + it * 16;
    *(bf16x8*)&XtE[r * 136 + sseg * 8] =
        *(const bf16x8*)&nxe[(cls * 128 + r) * 128 + sseg * 8];
  }
  if (t < 128) negl[t] = cspart[cls * 128 + t];
  __syncthreads();

  const int wv = t >> 6, lane = t & 63;
  const int quad = lane >> 4, lrow = lane & 15;
  f32x4 zero = {0.f, 0.f, 0.f, 0.f};
  f32x4 acc_i[8], acc_p[4];
  for (int j = 0; j < 8; j++) acc_i[j] = zero;
  for (int j = 0; j < 4; j++) acc_p[j] = zero;

  for (int kc = 0; kc < 4; kc++) {
    bf16x8 a = *(const bf16x8*)&Xt[(wv * 16 + lrow) * 136 + kc * 32 + quad * 8];
    for (int j = 0; j < 8; j++) {
      bf16x8 b = *(const bf16x8*)&XtE[(j * 16 + lrow) * 136 + kc * 32 + quad * 8];
      acc_i[j] = __builtin_amdgcn_mfma_f32_16x16x32_bf16(a, b, acc_i[j], 0, 0, 0);
    }
    for (int j = 0; j < 4; j++) {
      bf16x8 b = *(const bf16x8*)&PtE[(j * 16 + lrow) * 136 + kc * 32 + quad * 8];
      acc_p[j] = __builtin_amdgcn_mfma_f32_16x16x32_bf16(a, b, acc_p[j], 0, 0, 0);
    }
  }

  // proto term
  float wacc0 = 0.0f;
  for (int r = 0; r < 4; r++) {
    float tot = 0.0f;
    for (int j = 0; j < 4; j++) tot += exp2f(acc_p[j][r]);
    tot += __shfl_xor(tot, 1, 64);
    tot += __shfl_xor(tot, 2, 64);
    tot += __shfl_xor(tot, 4, 64);
    tot += __shfl_xor(tot, 8, 64);
    if (lrow == 0) wacc0 += logf(tot);
  }
  {
    const int jc = cls >> 4, colc = cls & 15;
    if (lrow == colc) {
      float sd = 0.0f;
      switch (jc) {
        case 0: for (int r = 0; r < 4; r++) sd += acc_p[0][r]; break;
        case 1: for (int r = 0; r < 4; r++) sd += acc_p[1][r]; break;
        case 2: for (int r = 0; r < 4; r++) sd += acc_p[2][r]; break;
        default: for (int r = 0; r < 4; r++) sd += acc_p[3][r]; break;
      }
      wacc0 -= sd * LN2F;
    }
  }
  // instance term
  float wacc1 = 0.0f;
  for (int j = 0; j < 8; j++) {
    float ng = negl[j * 16 + lrow];
    for (int r = 0; r < 4; r++)
      wacc1 += log1pf(ng * exp2f(-acc_i[j][r]));
  }
  for (int off = 32; off; off >>= 1) {
    wacc0 += __shfl_xor(wacc0, off, 64);
    wacc1 += __shfl_xor(wacc1, off, 64);
  }
  if (lane == 0) {
    atomicAdd(&accs[0], wacc0);
    atomicAdd(&accs[1], wacc1);
  }
  __syncthreads();
  if (t == 0) {
    __threadfence();
    unsigned int old = atomicAdd((unsigned int*)&accs[2], 1u);
    if (old == 127u) {
      __threadfence();
      float a0 = atomicAdd(&accs[0], 0.0f);
      float a1 = atomicAdd(&accs[1], 0.0f);
      out[0] = a0 * (1.0f / 524288.0f) + a1 * (1.0f / 67108864.0f);
    }
  }
}

// ---------------------------------------------------------------------------
extern "C" void kernel_launch(void* const* d_in, const int* in_sizes, int n_in,
                              void* d_out, int out_size, void* d_ws, size_t ws_size,
                              hipStream_t stream) {
  const float* e  = (const float*)d_in[0];   // embeds [64,128,768]
  const float* w  = (const float*)d_in[1];   // head_w [128,768]
  const float* hb = (const float*)d_in[2];   // head_b [128]
  const float* pr = (const float*)d_in[3];   // proto  [64,128]
  char* ws = (char*)d_ws;
  __bf16* nxb    = (__bf16*)ws;                        // 2 MB
  __bf16* nxe    = (__bf16*)(ws + (2 << 20));          // 2 MB
  float*  cspart = (float*)(ws + (4 << 20));           // 32 KB
  float*  accs   = (float*)(ws + (4 << 20) + (64 << 10));  // 16 B
  float*  out    = (float*)d_out;

  k_headnorm<<<256, 256, 0, stream>>>(e, w, hb, nxb, nxe, cspart, accs);
  k_colsum<<<dim3(64, 8), 256, 0, stream>>>(nxb, nxe, cspart);
  k_fused<<<dim3(64, 2), 256, 0, stream>>>(nxb, nxe, pr, cspart, accs, out);
}

// Round 6
// 131.367 us; speedup vs baseline: 1.1937x; 1.1937x over previous
//
#include <hip/hip_runtime.h>
#include <math.h>

#define SCALE_INV 20.0f
#define EXPK 28.853900817779268f   // SCALE_INV * log2(e)
#define LN2F 0.6931471805599453f   // SCALE_INV / EXPK

typedef __bf16 bf16x8 __attribute__((ext_vector_type(8)));
typedef float  f32x4  __attribute__((ext_vector_type(4)));

// ---------------------------------------------------------------------------
// 1. fused head GEMM + bias + l2norm -> nxb, nxe. grid 256 x 256 thr.
//    (round-2-proven structure). Also zeroes cspart + accs for later passes.
// ---------------------------------------------------------------------------
__global__ __launch_bounds__(256) void k_headnorm(const float* __restrict__ e,
                                                  const float* __restrict__ w,
                                                  const float* __restrict__ hb,
                                                  __bf16* __restrict__ nxb,
                                                  __bf16* __restrict__ nxe,
                                                  float* __restrict__ cspart,
                                                  float* __restrict__ accs) {
  __shared__ __bf16 Ab[32 * 72];    // 32 rows x 64 k
  __shared__ __bf16 Bb[128 * 72];   // 128 h  x 64 k
  __shared__ float  xt[32 * 132];   // output tile for norm
  __shared__ float  hbl[128];
  const int t  = threadIdx.x;
  const int rt = blockIdx.x;
  if (t < 128) hbl[t] = hb[t];
  if (t < 32) cspart[rt * 32 + t] = 0.0f;          // zero neg-accumulator
  if (rt == 0 && t >= 128 && t < 132) accs[t - 128] = 0.0f;

  const int arow = t >> 3, akoff = (t & 7) * 8;   // A: 8 floats/thread
  const int brow = t >> 1, bkoff = (t & 1) * 32;  // B: 32 floats/thread
  float4 ar[2], br[8];
  {
    const float* p = &e[(rt * 32 + arow) * 768 + akoff];
    ar[0] = *(const float4*)p; ar[1] = *(const float4*)(p + 4);
    const float* q = &w[brow * 768 + bkoff];
    for (int i = 0; i < 8; i++) br[i] = *(const float4*)(q + 4 * i);
  }

  const int wv = t >> 6, lane = t & 63;
  const int quad = lane >> 4, lrow = lane & 15;
  const int rb = wv & 1, cb = wv >> 1;
  f32x4 acc[4];
  f32x4 zero = {0.f, 0.f, 0.f, 0.f};
  for (int j = 0; j < 4; j++) acc[j] = zero;

  for (int it = 0; it < 12; it++) {
    {
      __bf16 ta[8];
      const float* f = (const float*)ar;
      for (int i = 0; i < 8; i++) ta[i] = (__bf16)f[i];
      *(bf16x8*)&Ab[arow * 72 + akoff] = *(bf16x8*)ta;
      const float* g = (const float*)br;
      for (int seg = 0; seg < 4; seg++) {
        __bf16 tb[8];
        for (int i = 0; i < 8; i++) tb[i] = (__bf16)g[seg * 8 + i];
        *(bf16x8*)&Bb[brow * 72 + bkoff + seg * 8] = *(bf16x8*)tb;
      }
    }
    __syncthreads();
    if (it < 11) {
      int kb = (it + 1) * 64;
      const float* p = &e[(rt * 32 + arow) * 768 + kb + akoff];
      ar[0] = *(const float4*)p; ar[1] = *(const float4*)(p + 4);
      const float* q = &w[brow * 768 + kb + bkoff];
      for (int i = 0; i < 8; i++) br[i] = *(const float4*)(q + 4 * i);
    }
    for (int kc = 0; kc < 2; kc++) {
      bf16x8 a = *(const bf16x8*)&Ab[(rb * 16 + lrow) * 72 + kc * 32 + quad * 8];
      for (int j = 0; j < 4; j++) {
        bf16x8 b = *(const bf16x8*)&Bb[(cb * 64 + j * 16 + lrow) * 72 + kc * 32 + quad * 8];
        acc[j] = __builtin_amdgcn_mfma_f32_16x16x32_bf16(a, b, acc[j], 0, 0, 0);
      }
    }
    __syncthreads();
  }

  for (int j = 0; j < 4; j++)
    for (int r = 0; r < 4; r++) {
      int row = rb * 16 + quad * 4 + r;
      int col = cb * 64 + j * 16 + lrow;
      xt[row * 132 + col] = acc[j][r] + hbl[col];
    }
  __syncthreads();
  {
    int row = t >> 3, c0 = (t & 7) * 16;
    float v[16];
    float s = 0.0f;
    for (int i = 0; i < 4; i++) {
      float4 f = *(const float4*)&xt[row * 132 + c0 + i * 4];
      v[i * 4] = f.x; v[i * 4 + 1] = f.y; v[i * 4 + 2] = f.z; v[i * 4 + 3] = f.w;
    }
    for (int i = 0; i < 16; i++) s += v[i] * v[i];
    s += __shfl_xor(s, 1, 64);
    s += __shfl_xor(s, 2, 64);
    s += __shfl_xor(s, 4, 64);
    float inv = 1.0f / fmaxf(sqrtf(s), 1e-12f);
    __bf16 o[16], oe[16];
    for (int i = 0; i < 16; i++) {
      float nv = v[i] * inv;
      o[i]  = (__bf16)nv;
      oe[i] = (__bf16)(nv * EXPK);
    }
    __bf16* dst = &nxb[(rt * 32 + row) * 128 + c0];
    *(bf16x8*)dst       = *(bf16x8*)o;
    *(bf16x8*)(dst + 8) = *(bf16x8*)(o + 8);
    __bf16* dse = &nxe[(rt * 32 + row) * 128 + c0];
    *(bf16x8*)dse       = *(bf16x8*)oe;
    *(bf16x8*)(dse + 8) = *(bf16x8*)(oe + 8);
  }
}

// ---------------------------------------------------------------------------
// 2. big MFMA pass. grid (64, 10), 256 thr, LDS = At+Bt+colpart = 71.7 KB.
//    rs in [0,8): symmetric off-class colsum (round-4 proven path, no hoist).
//    rs == 8 : in-class 128x128 logit tile -> posD (fp32, for k_last).
//    rs == 9 : proto term (protos normed in-LDS into Bt) -> accs[0].
// ---------------------------------------------------------------------------
__global__ __launch_bounds__(256) void k_colsum(const __bf16* __restrict__ nxb,
                                                const __bf16* __restrict__ nxe,
                                                const float* __restrict__ proto,
                                                float* __restrict__ cspart,
                                                float* __restrict__ posD,
                                                float* __restrict__ accs) {
  __shared__ __bf16 At[128 * 136];
  __shared__ __bf16 Bt[128 * 136];
  __shared__ float  colpart[4 * 128];
  const int t    = threadIdx.x;
  const int cj   = blockIdx.x;   // class
  const int rs   = blockIdx.y;
  const int w    = t >> 6, lane = t & 63;
  const int quad = lane >> 4, lrow = lane & 15;
  const int sr   = t >> 4, sseg = t & 15;

  if (rs < 8) {
    // ---------------- off-class symmetric pair path ----------------
    for (int it = 0; it < 8; it++) {
      int r = sr + it * 16;
      *(bf16x8*)&Bt[r * 136 + sseg * 8] =
          *(const bf16x8*)&nxe[(cj * 128 + r) * 128 + sseg * 8];
    }
    int tiles[4], nt = 0;
    for (int mm = 0; mm < 4; mm++) {
      int m = rs * 4 + 1 + mm;
      if (m < 32 || cj < 32) tiles[nt++] = (cj + m) & 63;
    }
    bf16x8 pre[8];
    for (int it = 0; it < 8; it++)
      pre[it] = *(const bf16x8*)&nxb[(tiles[0] * 128 + sr + it * 16) * 128 + sseg * 8];

    float colacc[8];
    for (int j = 0; j < 8; j++) colacc[j] = 0.0f;

    for (int ti = 0; ti < nt; ti++) {
      const int ci = tiles[ti];
      for (int it = 0; it < 8; it++)
        *(bf16x8*)&At[(sr + it * 16) * 136 + sseg * 8] = pre[it];
      __syncthreads();
      if (ti + 1 < nt) {
        int cn = tiles[ti + 1];
        for (int it = 0; it < 8; it++)
          pre[it] = *(const bf16x8*)&nxb[(cn * 128 + sr + it * 16) * 128 + sseg * 8];
      }
      f32x4 acc[2][8];
      f32x4 zero = {0.0f, 0.0f, 0.0f, 0.0f};
      for (int i = 0; i < 2; i++)
        for (int j = 0; j < 8; j++) acc[i][j] = zero;
      for (int kc = 0; kc < 4; kc++) {
        bf16x8 a0 = *(const bf16x8*)&At[(w * 32 + lrow) * 136 + kc * 32 + quad * 8];
        bf16x8 a1 = *(const bf16x8*)&At[(w * 32 + 16 + lrow) * 136 + kc * 32 + quad * 8];
        for (int j = 0; j < 8; j++) {
          bf16x8 b = *(const bf16x8*)&Bt[(j * 16 + lrow) * 136 + kc * 32 + quad * 8];
          acc[0][j] = __builtin_amdgcn_mfma_f32_16x16x32_bf16(a0, b, acc[0][j], 0, 0, 0);
          acc[1][j] = __builtin_amdgcn_mfma_f32_16x16x32_bf16(a1, b, acc[1][j], 0, 0, 0);
        }
      }
      float rsum[2][4];
      for (int i = 0; i < 2; i++)
        for (int r = 0; r < 4; r++) rsum[i][r] = 0.0f;
      for (int i = 0; i < 2; i++)
        for (int j = 0; j < 8; j++)
          for (int r = 0; r < 4; r++) {
            float ev = exp2f(acc[i][j][r]);
            colacc[j]  += ev;
            rsum[i][r] += ev;
          }
      for (int i = 0; i < 2; i++)
        for (int r = 0; r < 4; r++) {
          float v = rsum[i][r];
          v += __shfl_xor(v, 1, 64);
          v += __shfl_xor(v, 2, 64);
          v += __shfl_xor(v, 4, 64);
          v += __shfl_xor(v, 8, 64);
          if (lrow == 0)
            atomicAdd(&cspart[ci * 128 + w * 32 + i * 16 + quad * 4 + r], v);
        }
      __syncthreads();
    }

    for (int j = 0; j < 8; j++) {
      float v = colacc[j];
      v += __shfl_xor(v, 16, 64);
      v += __shfl_xor(v, 32, 64);
      if (lane < 16) colpart[w * 128 + j * 16 + lane] = v;
    }
    __syncthreads();
    if (t < 128) {
      float s = colpart[t] + colpart[128 + t] + colpart[256 + t] + colpart[384 + t];
      atomicAdd(&cspart[cj * 128 + t], s);
    }
  } else if (rs == 8) {
    // ---------------- diagonal (in-class) logits -> posD ----------------
    for (int it = 0; it < 8; it++) {
      int r = sr + it * 16;
      *(bf16x8*)&At[r * 136 + sseg * 8] =
          *(const bf16x8*)&nxb[(cj * 128 + r) * 128 + sseg * 8];
      *(bf16x8*)&Bt[r * 136 + sseg * 8] =
          *(const bf16x8*)&nxe[(cj * 128 + r) * 128 + sseg * 8];
    }
    __syncthreads();
    f32x4 acc[2][8];
    f32x4 zero = {0.0f, 0.0f, 0.0f, 0.0f};
    for (int i = 0; i < 2; i++)
      for (int j = 0; j < 8; j++) acc[i][j] = zero;
    for (int kc = 0; kc < 4; kc++) {
      bf16x8 a0 = *(const bf16x8*)&At[(w * 32 + lrow) * 136 + kc * 32 + quad * 8];
      bf16x8 a1 = *(const bf16x8*)&At[(w * 32 + 16 + lrow) * 136 + kc * 32 + quad * 8];
      for (int j = 0; j < 8; j++) {
        bf16x8 b = *(const bf16x8*)&Bt[(j * 16 + lrow) * 136 + kc * 32 + quad * 8];
        acc[0][j] = __builtin_amdgcn_mfma_f32_16x16x32_bf16(a0, b, acc[0][j], 0, 0, 0);
        acc[1][j] = __builtin_amdgcn_mfma_f32_16x16x32_bf16(a1, b, acc[1][j], 0, 0, 0);
      }
    }
    for (int i = 0; i < 2; i++)
      for (int j = 0; j < 8; j++)
        for (int r = 0; r < 4; r++) {
          int row = w * 32 + i * 16 + quad * 4 + r;
          int col = j * 16 + lrow;
          posD[cj * 16384 + row * 128 + col] = acc[i][j][r];
        }
  } else {
    // ---------------- proto term -> accs[0] ----------------
    for (int it = 0; it < 8; it++) {
      int r = sr + it * 16;
      *(bf16x8*)&At[r * 136 + sseg * 8] =
          *(const bf16x8*)&nxb[(cj * 128 + r) * 128 + sseg * 8];
    }
    {  // norm protos (x EXPK) into Bt rows 0..63
      const int rw = t >> 2, part = t & 3;
      float v[32];
      float s = 0.0f;
      const float* p = &proto[rw * 128 + part * 32];
      for (int i = 0; i < 8; i++) {
        float4 f = *(const float4*)(p + 4 * i);
        v[i * 4] = f.x; v[i * 4 + 1] = f.y; v[i * 4 + 2] = f.z; v[i * 4 + 3] = f.w;
        s += f.x * f.x + f.y * f.y + f.z * f.z + f.w * f.w;
      }
      s += __shfl_xor(s, 1, 64);
      s += __shfl_xor(s, 2, 64);
      float inv = EXPK / fmaxf(sqrtf(s), 1e-12f);
      __bf16 o[32];
      for (int i = 0; i < 32; i++) o[i] = (__bf16)(v[i] * inv);
      __bf16* dst = &Bt[rw * 136 + part * 32];
      for (int i = 0; i < 4; i++) *(bf16x8*)(dst + i * 8) = *(bf16x8*)(o + i * 8);
    }
    __syncthreads();
    f32x4 acc_p[2][4];
    f32x4 zero = {0.0f, 0.0f, 0.0f, 0.0f};
    for (int i = 0; i < 2; i++)
      for (int j = 0; j < 4; j++) acc_p[i][j] = zero;
    for (int kc = 0; kc < 4; kc++) {
      bf16x8 a0 = *(const bf16x8*)&At[(w * 32 + lrow) * 136 + kc * 32 + quad * 8];
      bf16x8 a1 = *(const bf16x8*)&At[(w * 32 + 16 + lrow) * 136 + kc * 32 + quad * 8];
      for (int j = 0; j < 4; j++) {
        bf16x8 b = *(const bf16x8*)&Bt[(j * 16 + lrow) * 136 + kc * 32 + quad * 8];
        acc_p[0][j] = __builtin_amdgcn_mfma_f32_16x16x32_bf16(a0, b, acc_p[0][j], 0, 0, 0);
        acc_p[1][j] = __builtin_amdgcn_mfma_f32_16x16x32_bf16(a1, b, acc_p[1][j], 0, 0, 0);
      }
    }
    float wacc0 = 0.0f;
    for (int i = 0; i < 2; i++) {
      for (int r = 0; r < 4; r++) {
        float tot = 0.0f;
        for (int j = 0; j < 4; j++) tot += exp2f(acc_p[i][j][r]);
        tot += __shfl_xor(tot, 1, 64);
        tot += __shfl_xor(tot, 2, 64);
        tot += __shfl_xor(tot, 4, 64);
        tot += __shfl_xor(tot, 8, 64);
        if (lrow == 0) wacc0 += logf(tot);
      }
      const int jc = cj >> 4, colc = cj & 15;
      if (lrow == colc) {
        float sd = 0.0f;
        switch (jc) {
          case 0: for (int r = 0; r < 4; r++) sd += acc_p[i][0][r]; break;
          case 1: for (int r = 0; r < 4; r++) sd += acc_p[i][1][r]; break;
          case 2: for (int r = 0; r < 4; r++) sd += acc_p[i][2][r]; break;
          default: for (int r = 0; r < 4; r++) sd += acc_p[i][3][r]; break;
        }
        wacc0 -= sd * LN2F;
      }
    }
    for (int off = 32; off; off >>= 1) wacc0 += __shfl_xor(wacc0, off, 64);
    if (lane == 0) atomicAdd(&accs[0], wacc0);
  }
}

// ---------------------------------------------------------------------------
// 3. instance-loss streaming pass + finalize. grid 256 x 256 thr.
//    block b: class b>>2, m-rows (b&3)*32 .. +32 (4096 elements of posD).
// ---------------------------------------------------------------------------
__global__ __launch_bounds__(256) void k_last(const float* __restrict__ posD,
                                              const float* __restrict__ cspart,
                                              float* __restrict__ accs,
                                              float* __restrict__ out) {
  __shared__ float negl[128];
  __shared__ float wred[4];
  const int b = blockIdx.x, t = threadIdx.x;
  const int cls = b >> 2, m0 = (b & 3) * 32;
  if (t < 128) negl[t] = cspart[cls * 128 + t];
  __syncthreads();
  const float* base = &posD[cls * 16384 + m0 * 128];
  float wacc = 0.0f;
  for (int it = 0; it < 4; it++) {
    int idx = (it * 256 + t) * 4;
    float4 d = *(const float4*)&base[idx];
    int n = idx & 127;
    wacc += log1pf(negl[n]     * exp2f(-d.x));
    wacc += log1pf(negl[n + 1] * exp2f(-d.y));
    wacc += log1pf(negl[n + 2] * exp2f(-d.z));
    wacc += log1pf(negl[n + 3] * exp2f(-d.w));
  }
  for (int off = 32; off; off >>= 1) wacc += __shfl_xor(wacc, off, 64);
  if ((t & 63) == 0) wred[t >> 6] = wacc;
  __syncthreads();
  if (t == 0) {
    atomicAdd(&accs[1], wred[0] + wred[1] + wred[2] + wred[3]);
    __threadfence();
    unsigned int old = atomicAdd((unsigned int*)&accs[3], 1u);
    if (old == 255u) {
      __threadfence();
      float a0 = atomicAdd(&accs[0], 0.0f);
      float a1 = atomicAdd(&accs[1], 0.0f);
      out[0] = a0 * (1.0f / 524288.0f) + a1 * (1.0f / 67108864.0f);
    }
  }
}

// ---------------------------------------------------------------------------
extern "C" void kernel_launch(void* const* d_in, const int* in_sizes, int n_in,
                              void* d_out, int out_size, void* d_ws, size_t ws_size,
                              hipStream_t stream) {
  const float* e  = (const float*)d_in[0];   // embeds [64,128,768]
  const float* w  = (const float*)d_in[1];   // head_w [128,768]
  const float* hb = (const float*)d_in[2];   // head_b [128]
  const float* pr = (const float*)d_in[3];   // proto  [64,128]
  char* ws = (char*)d_ws;
  __bf16* nxb    = (__bf16*)ws;                            // 2 MB
  __bf16* nxe    = (__bf16*)(ws + (2 << 20));              // 2 MB
  float*  cspart = (float*)(ws + (4 << 20));               // 32 KB
  float*  accs   = (float*)(ws + (4 << 20) + (64 << 10));  // 16 B
  float*  posD   = (float*)(ws + (5 << 20));               // 4 MB
  float*  out    = (float*)d_out;

  k_headnorm<<<256, 256, 0, stream>>>(e, w, hb, nxb, nxe, cspart, accs);
  k_colsum<<<dim3(64, 10), 256, 0, stream>>>(nxb, nxe, pr, cspart, posD, accs);
  k_last<<<256, 256, 0, stream>>>(posD, cspart, accs, out);
}

// Round 7
// 123.847 us; speedup vs baseline: 1.2662x; 1.0607x over previous
//
#include <hip/hip_runtime.h>
#include <math.h>

#define SCALE_INV 20.0f
#define EXPK 28.853900817779268f   // SCALE_INV * log2(e)
#define LN2F 0.6931471805599453f   // SCALE_INV / EXPK

typedef __bf16 bf16x8 __attribute__((ext_vector_type(8)));
typedef __bf16 bf16x4 __attribute__((ext_vector_type(4)));
typedef float  f32x4  __attribute__((ext_vector_type(4)));

// ---------------------------------------------------------------------------
// 0. prep: w -> bf16 (once, instead of per-headnorm-block); zero cspart/accs.
//    grid 96 x 256 (96*256*4 = 98304 = 128*768).
// ---------------------------------------------------------------------------
__global__ __launch_bounds__(256) void k_prep(const float* __restrict__ w,
                                              __bf16* __restrict__ wb,
                                              float* __restrict__ cspart,
                                              float* __restrict__ accs) {
  const int b = blockIdx.x, t = threadIdx.x;
  int i = (b * 256 + t) * 4;
  float4 f = *(const float4*)&w[i];
  __bf16 o[4] = {(__bf16)f.x, (__bf16)f.y, (__bf16)f.z, (__bf16)f.w};
  *(bf16x4*)&wb[i] = *(bf16x4*)o;
  if (b < 64 && t < 128) cspart[b * 128 + t] = 0.0f;
  if (b == 95 && t < 4) accs[t] = 0.0f;
}

// ---------------------------------------------------------------------------
// 1. fused head GEMM + bias + l2norm -> nxb, nxe. grid 256 x 256 thr.
//    32 rows/block, K-chunks of 128 (6 iters), bf16 w staged directly.
//    Same K accumulation order as before -> bit-identical output.
// ---------------------------------------------------------------------------
__global__ __launch_bounds__(256) void k_headnorm(const float* __restrict__ e,
                                                  const __bf16* __restrict__ wb,
                                                  const float* __restrict__ hb,
                                                  __bf16* __restrict__ nxb,
                                                  __bf16* __restrict__ nxe) {
  __shared__ __bf16 Ab[32 * 136];   // 32 rows x 128 k
  __shared__ __bf16 Bb[128 * 136];  // 128 h  x 128 k
  __shared__ float  xt[32 * 132];   // output tile for norm
  __shared__ float  hbl[128];
  const int t  = threadIdx.x;
  const int rt = blockIdx.x;
  if (t < 128) hbl[t] = hb[t];

  const int arow = t >> 3, akoff = (t & 7) * 16;  // A: 16 floats/thread
  const int brow = t >> 1, bkoff = (t & 1) * 64;  // B: 64 bf16/thread
  float4 ar[4];
  bf16x8 brg[8];
  {
    const float* p = &e[(rt * 32 + arow) * 768 + akoff];
    for (int i = 0; i < 4; i++) ar[i] = *(const float4*)(p + 4 * i);
    const __bf16* q = &wb[brow * 768 + bkoff];
    for (int i = 0; i < 8; i++) brg[i] = *(const bf16x8*)(q + 8 * i);
  }

  const int wv = t >> 6, lane = t & 63;
  const int quad = lane >> 4, lrow = lane & 15;
  const int rb = wv & 1, cb = wv >> 1;
  f32x4 acc[4];
  f32x4 zero = {0.f, 0.f, 0.f, 0.f};
  for (int j = 0; j < 4; j++) acc[j] = zero;

  for (int it = 0; it < 6; it++) {
    {
      __bf16 ta[16];
      const float* f = (const float*)ar;
      for (int i = 0; i < 16; i++) ta[i] = (__bf16)f[i];
      *(bf16x8*)&Ab[arow * 136 + akoff]     = *(bf16x8*)ta;
      *(bf16x8*)&Ab[arow * 136 + akoff + 8] = *(bf16x8*)(ta + 8);
      for (int seg = 0; seg < 8; seg++)
        *(bf16x8*)&Bb[brow * 136 + bkoff + seg * 8] = brg[seg];
    }
    __syncthreads();
    if (it < 5) {
      int kb = (it + 1) * 128;
      const float* p = &e[(rt * 32 + arow) * 768 + kb + akoff];
      for (int i = 0; i < 4; i++) ar[i] = *(const float4*)(p + 4 * i);
      const __bf16* q = &wb[brow * 768 + kb + bkoff];
      for (int i = 0; i < 8; i++) brg[i] = *(const bf16x8*)(q + 8 * i);
    }
    for (int kc = 0; kc < 4; kc++) {
      bf16x8 a = *(const bf16x8*)&Ab[(rb * 16 + lrow) * 136 + kc * 32 + quad * 8];
      for (int j = 0; j < 4; j++) {
        bf16x8 b = *(const bf16x8*)&Bb[(cb * 64 + j * 16 + lrow) * 136 + kc * 32 + quad * 8];
        acc[j] = __builtin_amdgcn_mfma_f32_16x16x32_bf16(a, b, acc[j], 0, 0, 0);
      }
    }
    __syncthreads();
  }

  for (int j = 0; j < 4; j++)
    for (int r = 0; r < 4; r++) {
      int row = rb * 16 + quad * 4 + r;
      int col = cb * 64 + j * 16 + lrow;
      xt[row * 132 + col] = acc[j][r] + hbl[col];
    }
  __syncthreads();
  {
    int row = t >> 3, c0 = (t & 7) * 16;
    float v[16];
    float s = 0.0f;
    for (int i = 0; i < 4; i++) {
      float4 f = *(const float4*)&xt[row * 132 + c0 + i * 4];
      v[i * 4] = f.x; v[i * 4 + 1] = f.y; v[i * 4 + 2] = f.z; v[i * 4 + 3] = f.w;
    }
    for (int i = 0; i < 16; i++) s += v[i] * v[i];
    s += __shfl_xor(s, 1, 64);
    s += __shfl_xor(s, 2, 64);
    s += __shfl_xor(s, 4, 64);
    float inv = 1.0f / fmaxf(sqrtf(s), 1e-12f);
    __bf16 o[16], oe[16];
    for (int i = 0; i < 16; i++) {
      float nv = v[i] * inv;
      o[i]  = (__bf16)nv;
      oe[i] = (__bf16)(nv * EXPK);
    }
    __bf16* dst = &nxb[(rt * 32 + row) * 128 + c0];
    *(bf16x8*)dst       = *(bf16x8*)o;
    *(bf16x8*)(dst + 8) = *(bf16x8*)(o + 8);
    __bf16* dse = &nxe[(rt * 32 + row) * 128 + c0];
    *(bf16x8*)dse       = *(bf16x8*)oe;
    *(bf16x8*)(dse + 8) = *(bf16x8*)(oe + 8);
  }
}

// ---------------------------------------------------------------------------
// 2. big MFMA pass. grid (64, 10), 256 thr, LDS = At+Bt+colpart = 71.7 KB.
//    rs in [0,8): symmetric off-class colsum (round-4 proven path).
//    rs == 8 : in-class 128x128 logit tile -> posD (fp32, for k_last).
//    rs == 9 : proto term (protos normed in-LDS into Bt) -> accs[0].
//    (unchanged from round 6)
// ---------------------------------------------------------------------------
__global__ __launch_bounds__(256) void k_colsum(const __bf16* __restrict__ nxb,
                                                const __bf16* __restrict__ nxe,
                                                const float* __restrict__ proto,
                                                float* __restrict__ cspart,
                                                float* __restrict__ posD,
                                                float* __restrict__ accs) {
  __shared__ __bf16 At[128 * 136];
  __shared__ __bf16 Bt[128 * 136];
  __shared__ float  colpart[4 * 128];
  const int t    = threadIdx.x;
  const int cj   = blockIdx.x;   // class
  const int rs   = blockIdx.y;
  const int w    = t >> 6, lane = t & 63;
  const int quad = lane >> 4, lrow = lane & 15;
  const int sr   = t >> 4, sseg = t & 15;

  if (rs < 8) {
    // ---------------- off-class symmetric pair path ----------------
    for (int it = 0; it < 8; it++) {
      int r = sr + it * 16;
      *(bf16x8*)&Bt[r * 136 + sseg * 8] =
          *(const bf16x8*)&nxe[(cj * 128 + r) * 128 + sseg * 8];
    }
    int tiles[4], nt = 0;
    for (int mm = 0; mm < 4; mm++) {
      int m = rs * 4 + 1 + mm;
      if (m < 32 || cj < 32) tiles[nt++] = (cj + m) & 63;
    }
    bf16x8 pre[8];
    for (int it = 0; it < 8; it++)
      pre[it] = *(const bf16x8*)&nxb[(tiles[0] * 128 + sr + it * 16) * 128 + sseg * 8];

    float colacc[8];
    for (int j = 0; j < 8; j++) colacc[j] = 0.0f;

    for (int ti = 0; ti < nt; ti++) {
      const int ci = tiles[ti];
      for (int it = 0; it < 8; it++)
        *(bf16x8*)&At[(sr + it * 16) * 136 + sseg * 8] = pre[it];
      __syncthreads();
      if (ti + 1 < nt) {
        int cn = tiles[ti + 1];
        for (int it = 0; it < 8; it++)
          pre[it] = *(const bf16x8*)&nxb[(cn * 128 + sr + it * 16) * 128 + sseg * 8];
      }
      f32x4 acc[2][8];
      f32x4 zero = {0.0f, 0.0f, 0.0f, 0.0f};
      for (int i = 0; i < 2; i++)
        for (int j = 0; j < 8; j++) acc[i][j] = zero;
      for (int kc = 0; kc < 4; kc++) {
        bf16x8 a0 = *(const bf16x8*)&At[(w * 32 + lrow) * 136 + kc * 32 + quad * 8];
        bf16x8 a1 = *(const bf16x8*)&At[(w * 32 + 16 + lrow) * 136 + kc * 32 + quad * 8];
        for (int j = 0; j < 8; j++) {
          bf16x8 b = *(const bf16x8*)&Bt[(j * 16 + lrow) * 136 + kc * 32 + quad * 8];
          acc[0][j] = __builtin_amdgcn_mfma_f32_16x16x32_bf16(a0, b, acc[0][j], 0, 0, 0);
          acc[1][j] = __builtin_amdgcn_mfma_f32_16x16x32_bf16(a1, b, acc[1][j], 0, 0, 0);
        }
      }
      float rsum[2][4];
      for (int i = 0; i < 2; i++)
        for (int r = 0; r < 4; r++) rsum[i][r] = 0.0f;
      for (int i = 0; i < 2; i++)
        for (int j = 0; j < 8; j++)
          for (int r = 0; r < 4; r++) {
            float ev = exp2f(acc[i][j][r]);
            colacc[j]  += ev;
            rsum[i][r] += ev;
          }
      for (int i = 0; i < 2; i++)
        for (int r = 0; r < 4; r++) {
          float v = rsum[i][r];
          v += __shfl_xor(v, 1, 64);
          v += __shfl_xor(v, 2, 64);
          v += __shfl_xor(v, 4, 64);
          v += __shfl_xor(v, 8, 64);
          if (lrow == 0)
            atomicAdd(&cspart[ci * 128 + w * 32 + i * 16 + quad * 4 + r], v);
        }
      __syncthreads();
    }

    for (int j = 0; j < 8; j++) {
      float v = colacc[j];
      v += __shfl_xor(v, 16, 64);
      v += __shfl_xor(v, 32, 64);
      if (lane < 16) colpart[w * 128 + j * 16 + lane] = v;
    }
    __syncthreads();
    if (t < 128) {
      float s = colpart[t] + colpart[128 + t] + colpart[256 + t] + colpart[384 + t];
      atomicAdd(&cspart[cj * 128 + t], s);
    }
  } else if (rs == 8) {
    // ---------------- diagonal (in-class) logits -> posD ----------------
    for (int it = 0; it < 8; it++) {
      int r = sr + it * 16;
      *(bf16x8*)&At[r * 136 + sseg * 8] =
          *(const bf16x8*)&nxb[(cj * 128 + r) * 128 + sseg * 8];
      *(bf16x8*)&Bt[r * 136 + sseg * 8] =
          *(const bf16x8*)&nxe[(cj * 128 + r) * 128 + sseg * 8];
    }
    __syncthreads();
    f32x4 acc[2][8];
    f32x4 zero = {0.0f, 0.0f, 0.0f, 0.0f};
    for (int i = 0; i < 2; i++)
      for (int j = 0; j < 8; j++) acc[i][j] = zero;
    for (int kc = 0; kc < 4; kc++) {
      bf16x8 a0 = *(const bf16x8*)&At[(w * 32 + lrow) * 136 + kc * 32 + quad * 8];
      bf16x8 a1 = *(const bf16x8*)&At[(w * 32 + 16 + lrow) * 136 + kc * 32 + quad * 8];
      for (int j = 0; j < 8; j++) {
        bf16x8 b = *(const bf16x8*)&Bt[(j * 16 + lrow) * 136 + kc * 32 + quad * 8];
        acc[0][j] = __builtin_amdgcn_mfma_f32_16x16x32_bf16(a0, b, acc[0][j], 0, 0, 0);
        acc[1][j] = __builtin_amdgcn_mfma_f32_16x16x32_bf16(a1, b, acc[1][j], 0, 0, 0);
      }
    }
    for (int i = 0; i < 2; i++)
      for (int j = 0; j < 8; j++)
        for (int r = 0; r < 4; r++) {
          int row = w * 32 + i * 16 + quad * 4 + r;
          int col = j * 16 + lrow;
          posD[cj * 16384 + row * 128 + col] = acc[i][j][r];
        }
  } else {
    // ---------------- proto term -> accs[0] ----------------
    for (int it = 0; it < 8; it++) {
      int r = sr + it * 16;
      *(bf16x8*)&At[r * 136 + sseg * 8] =
          *(const bf16x8*)&nxb[(cj * 128 + r) * 128 + sseg * 8];
    }
    {  // norm protos (x EXPK) into Bt rows 0..63
      const int rw = t >> 2, part = t & 3;
      float v[32];
      float s = 0.0f;
      const float* p = &proto[rw * 128 + part * 32];
      for (int i = 0; i < 8; i++) {
        float4 f = *(const float4*)(p + 4 * i);
        v[i * 4] = f.x; v[i * 4 + 1] = f.y; v[i * 4 + 2] = f.z; v[i * 4 + 3] = f.w;
        s += f.x * f.x + f.y * f.y + f.z * f.z + f.w * f.w;
      }
      s += __shfl_xor(s, 1, 64);
      s += __shfl_xor(s, 2, 64);
      float inv = EXPK / fmaxf(sqrtf(s), 1e-12f);
      __bf16 o[32];
      for (int i = 0; i < 32; i++) o[i] = (__bf16)(v[i] * inv);
      __bf16* dst = &Bt[rw * 136 + part * 32];
      for (int i = 0; i < 4; i++) *(bf16x8*)(dst + i * 8) = *(bf16x8*)(o + i * 8);
    }
    __syncthreads();
    f32x4 acc_p[2][4];
    f32x4 zero = {0.0f, 0.0f, 0.0f, 0.0f};
    for (int i = 0; i < 2; i++)
      for (int j = 0; j < 4; j++) acc_p[i][j] = zero;
    for (int kc = 0; kc < 4; kc++) {
      bf16x8 a0 = *(const bf16x8*)&At[(w * 32 + lrow) * 136 + kc * 32 + quad * 8];
      bf16x8 a1 = *(const bf16x8*)&At[(w * 32 + 16 + lrow) * 136 + kc * 32 + quad * 8];
      for (int j = 0; j < 4; j++) {
        bf16x8 b = *(const bf16x8*)&Bt[(j * 16 + lrow) * 136 + kc * 32 + quad * 8];
        acc_p[0][j] = __builtin_amdgcn_mfma_f32_16x16x32_bf16(a0, b, acc_p[0][j], 0, 0, 0);
        acc_p[1][j] = __builtin_amdgcn_mfma_f32_16x16x32_bf16(a1, b, acc_p[1][j], 0, 0, 0);
      }
    }
    float wacc0 = 0.0f;
    for (int i = 0; i < 2; i++) {
      for (int r = 0; r < 4; r++) {
        float tot = 0.0f;
        for (int j = 0; j < 4; j++) tot += exp2f(acc_p[i][j][r]);
        tot += __shfl_xor(tot, 1, 64);
        tot += __shfl_xor(tot, 2, 64);
        tot += __shfl_xor(tot, 4, 64);
        tot += __shfl_xor(tot, 8, 64);
        if (lrow == 0) wacc0 += logf(tot);
      }
      const int jc = cj >> 4, colc = cj & 15;
      if (lrow == colc) {
        float sd = 0.0f;
        switch (jc) {
          case 0: for (int r = 0; r < 4; r++) sd += acc_p[i][0][r]; break;
          case 1: for (int r = 0; r < 4; r++) sd += acc_p[i][1][r]; break;
          case 2: for (int r = 0; r < 4; r++) sd += acc_p[i][2][r]; break;
          default: for (int r = 0; r < 4; r++) sd += acc_p[i][3][r]; break;
        }
        wacc0 -= sd * LN2F;
      }
    }
    for (int off = 32; off; off >>= 1) wacc0 += __shfl_xor(wacc0, off, 64);
    if (lane == 0) atomicAdd(&accs[0], wacc0);
  }
}

// ---------------------------------------------------------------------------
// 3. instance-loss streaming pass + finalize. grid 256 x 256 thr.
//    (unchanged from round 6)
// ---------------------------------------------------------------------------
__global__ __launch_bounds__(256) void k_last(const float* __restrict__ posD,
                                              const float* __restrict__ cspart,
                                              float* __restrict__ accs,
                                              float* __restrict__ out) {
  __shared__ float negl[128];
  __shared__ float wred[4];
  const int b = blockIdx.x, t = threadIdx.x;
  const int cls = b >> 2, m0 = (b & 3) * 32;
  if (t < 128) negl[t] = cspart[cls * 128 + t];
  __syncthreads();
  const float* base = &posD[cls * 16384 + m0 * 128];
  float wacc = 0.0f;
  for (int it = 0; it < 4; it++) {
    int idx = (it * 256 + t) * 4;
    float4 d = *(const float4*)&base[idx];
    int n = idx & 127;
    wacc += log1pf(negl[n]     * exp2f(-d.x));
    wacc += log1pf(negl[n + 1] * exp2f(-d.y));
    wacc += log1pf(negl[n + 2] * exp2f(-d.z));
    wacc += log1pf(negl[n + 3] * exp2f(-d.w));
  }
  for (int off = 32; off; off >>= 1) wacc += __shfl_xor(wacc, off, 64);
  if ((t & 63) == 0) wred[t >> 6] = wacc;
  __syncthreads();
  if (t == 0) {
    atomicAdd(&accs[1], wred[0] + wred[1] + wred[2] + wred[3]);
    __threadfence();
    unsigned int old = atomicAdd((unsigned int*)&accs[3], 1u);
    if (old == 255u) {
      __threadfence();
      float a0 = atomicAdd(&accs[0], 0.0f);
      float a1 = atomicAdd(&accs[1], 0.0f);
      out[0] = a0 * (1.0f / 524288.0f) + a1 * (1.0f / 67108864.0f);
    }
  }
}

// ---------------------------------------------------------------------------
extern "C" void kernel_launch(void* const* d_in, const int* in_sizes, int n_in,
                              void* d_out, int out_size, void* d_ws, size_t ws_size,
                              hipStream_t stream) {
  const float* e  = (const float*)d_in[0];   // embeds [64,128,768]
  const float* w  = (const float*)d_in[1];   // head_w [128,768]
  const float* hb = (const float*)d_in[2];   // head_b [128]
  const float* pr = (const float*)d_in[3];   // proto  [64,128]
  char* ws = (char*)d_ws;
  __bf16* nxb    = (__bf16*)ws;                            // 2 MB
  __bf16* nxe    = (__bf16*)(ws + (2 << 20));              // 2 MB
  float*  cspart = (float*)(ws + (4 << 20));               // 32 KB
  float*  accs   = (float*)(ws + (4 << 20) + (64 << 10));  // 16 B
  float*  posD   = (float*)(ws + (5 << 20));               // 4 MB
  __bf16* wb     = (__bf16*)(ws + (9 << 20));              // 192 KB
  float*  out    = (float*)d_out;

  k_prep<<<96, 256, 0, stream>>>(w, wb, cspart, accs);
  k_headnorm<<<256, 256, 0, stream>>>(e, wb, hb, nxb, nxe);
  k_colsum<<<dim3(64, 10), 256, 0, stream>>>(nxb, nxe, pr, cspart, posD, accs);
  k_last<<<256, 256, 0, stream>>>(posD, cspart, accs, out);
}